// Round 5
// baseline (280.230 us; speedup 1.0000x reference)
//
#include <hip/hip_runtime.h>

#define SPS    16
#define NS     8192            // symbols per batch row
#define NBITS  16384           // bits per batch row
#define UPLEN  (NS * SPS)      // 131072
#define KTAPS  128
#define QPB    256             // symbols (q values) handled per block
#define SWIN   264             // QPB + 8 halo

typedef float vfloat4 __attribute__((ext_vector_type(4)));

// Thread (g = tid>>3, k = tid&7) computes phases (2k, 2k+1) of q = q0+8g+r,
// r = 0..7. Output vfloat4 per (q,k): (re[2k], im[2k], re[2k+1], im[2k+1]) at
// float offset 32q + 4k -> lanes k=0..7 cover 128 contiguous bytes per store.
//
// Sample t=16q+p needs taps rrc[16i + 7-p] (p<8, symbol q+i-4) or
// rrc[16i + 23-p] (p>=8, symbol q+i-3), i=0..7. For the fixed phase pair:
//   off = k<4 ? 6-2k : 22-2k;  tap rrc[16i+off+1] -> phase 2k,
//                              tap rrc[16i+off]   -> phase 2k+1
// The p>=8 symbol shift is folded into the LDS window base address
// (base = g*8 + (k>=4)), so no register-level select is needed.
//
// R5 A/B: plain stores (no nt) — everything else identical to R4.
__global__ __launch_bounds__(256, 4)
void qpsk_mod_kernel(const int* __restrict__ bits,
                     const float* __restrict__ rrc,
                     float* __restrict__ out) {
    __shared__ float s_taps[KTAPS];
    __shared__ float s_re[SWIN];
    __shared__ float s_im[SWIN];

    const int tid = threadIdx.x;
    const int b   = blockIdx.x >> 5;           // 32 blocks per batch row
    const int q0  = (blockIdx.x & 31) * QPB;

    if (tid < KTAPS) s_taps[tid] = rrc[tid];

    const float scale = 2.82842712474619f;     // 4 / sqrt(2): sqrt(sps)/sqrt(2)
    for (int ls = tid; ls < SWIN; ls += 256) {
        int s = q0 - 4 + ls;                   // global symbol index
        float re = 0.f, im = 0.f;
        if (s >= 0 && s < NS) {
            int2 bb = *(const int2*)(bits + b * NBITS + 2 * s);
            re = (float)(1 - 2 * bb.y) * scale;
            im = (float)(1 - 2 * bb.x) * scale;
        }
        s_re[ls] = re;
        s_im[ls] = im;
    }
    __syncthreads();

    const int k    = tid & 7;
    const int g    = tid >> 3;
    const int off  = (k < 4) ? (6 - 2 * k) : (22 - 2 * k);
    const int base = g * 8 + (k >= 4 ? 1 : 0);

    // taps: one pair per tap-group (8 x ds_read_b64, wave-broadcast friendly)
    float tlo[8], thi[8];
#pragma unroll
    for (int i = 0; i < 8; ++i) {
        float2 tp = *(const float2*)(&s_taps[16 * i + off]);
        tlo[i] = tp.x;                         // -> phase 2k+1
        thi[i] = tp.y;                         // -> phase 2k
    }

    // 15-symbol window, sel folded into base (scalar LDS reads, 2-way banks)
    float sre[15], sim[15];
#pragma unroll
    for (int j = 0; j < 15; ++j) {
        sre[j] = s_re[base + j];
        sim[j] = s_im[base + j];
    }

    float* outp = out + (size_t)b * (UPLEN * 2)
                      + (size_t)(q0 + g * 8) * 32 + 4 * k;
#pragma unroll
    for (int r = 0; r < 8; ++r) {
        float a0 = 0.f, a1 = 0.f, a2 = 0.f, a3 = 0.f;
#pragma unroll
        for (int i = 0; i < 8; ++i) {
            float sr = sre[r + i];
            float si = sim[r + i];
            a0 += thi[i] * sr;                 // re, phase 2k
            a1 += thi[i] * si;                 // im, phase 2k
            a2 += tlo[i] * sr;                 // re, phase 2k+1
            a3 += tlo[i] * si;                 // im, phase 2k+1
        }
        vfloat4 v = {a0, a1, a2, a3};
        *(vfloat4*)(outp + 32 * r) = v;
    }
}

extern "C" void kernel_launch(void* const* d_in, const int* in_sizes, int n_in,
                              void* d_out, int out_size, void* d_ws, size_t ws_size,
                              hipStream_t stream) {
    const int*   bits = (const int*)d_in[0];
    const float* rrc  = (const float*)d_in[1];
    float*       out  = (float*)d_out;

    const int B = in_sizes[0] / NBITS;         // 256
    dim3 grid(B * (NS / QPB));                 // 8192 blocks
    qpsk_mod_kernel<<<grid, 256, 0, stream>>>(bits, rrc, out);
}

// Round 6
// 272.722 us; speedup vs baseline: 1.0275x; 1.0275x over previous
//
#include <hip/hip_runtime.h>

#define SPS    16
#define NS     8192            // symbols per batch row
#define NBITS  16384           // bits per batch row
#define UPLEN  (NS * SPS)      // 131072
#define KTAPS  128
#define QPB    256             // symbols (q values) handled per block
#define SWIN   264             // QPB + 8 halo

typedef float vfloat4 __attribute__((ext_vector_type(4)));

// R6: fully-contiguous wave stores. Thread (gg = tid>>3, k = tid&7) computes
// phases (2k, 2k+1) of q = q0 + G*32 + gg, G = 0..7 (loop). Store offset =
// q*128 + k*16 bytes = const(G,wave) + lane*16 -> each wave store instruction
// is one contiguous 1-KB burst (identical pattern to the 6.2-TB/s fill).
//
// Sample t=16q+p needs taps rrc[16i + 7-p] (p<8, symbol q+i-4) or
// rrc[16i + 23-p] (p>=8, symbol q+i-3), i=0..7. For the fixed phase pair:
//   off = k<4 ? 6-2k : 22-2k;  tap rrc[16i+off+1] -> phase 2k,
//                              tap rrc[16i+off]   -> phase 2k+1
//   sel = (k>=4) folded into the LDS window base address.
// Per-G symbol reads are 8-lane broadcasts across 8 consecutive banks
// (conflict-free).
__global__ __launch_bounds__(256, 4)
void qpsk_mod_kernel(const int* __restrict__ bits,
                     const float* __restrict__ rrc,
                     float* __restrict__ out) {
    __shared__ float s_taps[KTAPS];
    __shared__ float s_re[SWIN];
    __shared__ float s_im[SWIN];

    const int tid = threadIdx.x;
    const int b   = blockIdx.x >> 5;           // 32 blocks per batch row
    const int q0  = (blockIdx.x & 31) * QPB;

    if (tid < KTAPS) s_taps[tid] = rrc[tid];

    const float scale = 2.82842712474619f;     // 4 / sqrt(2): sqrt(sps)/sqrt(2)
    for (int ls = tid; ls < SWIN; ls += 256) {
        int s = q0 - 4 + ls;                   // global symbol index
        float re = 0.f, im = 0.f;
        if (s >= 0 && s < NS) {
            int2 bb = *(const int2*)(bits + b * NBITS + 2 * s);
            re = (float)(1 - 2 * bb.y) * scale;
            im = (float)(1 - 2 * bb.x) * scale;
        }
        s_re[ls] = re;
        s_im[ls] = im;
    }
    __syncthreads();

    const int k   = tid & 7;
    const int gg  = tid >> 3;                  // 0..31
    const int off = (k < 4) ? (6 - 2 * k) : (22 - 2 * k);
    const int sel = (k >= 4) ? 1 : 0;

    // taps: one pair per tap-group (8 x ds_read_b64, 8-lane broadcast)
    float tlo[8], thi[8];
#pragma unroll
    for (int i = 0; i < 8; ++i) {
        float2 tp = *(const float2*)(&s_taps[16 * i + off]);
        tlo[i] = tp.x;                         // -> phase 2k+1
        thi[i] = tp.y;                         // -> phase 2k
    }

    float* outp = out + (size_t)b * (UPLEN * 2)
                      + (size_t)q0 * 32 + (size_t)gg * 32 + 4 * k;

#pragma unroll
    for (int G = 0; G < 8; ++G) {
        const int wbase = G * 32 + gg + sel;   // LDS index of symbol q-4+sel
        float a0 = 0.f, a1 = 0.f, a2 = 0.f, a3 = 0.f;
#pragma unroll
        for (int i = 0; i < 8; ++i) {
            float sr = s_re[wbase + i];
            float si = s_im[wbase + i];
            a0 += thi[i] * sr;                 // re, phase 2k
            a1 += thi[i] * si;                 // im, phase 2k
            a2 += tlo[i] * sr;                 // re, phase 2k+1
            a3 += tlo[i] * si;                 // im, phase 2k+1
        }
        vfloat4 v = {a0, a1, a2, a3};
        __builtin_nontemporal_store(v, (vfloat4*)(outp + G * (32 * 32)));
    }
}

extern "C" void kernel_launch(void* const* d_in, const int* in_sizes, int n_in,
                              void* d_out, int out_size, void* d_ws, size_t ws_size,
                              hipStream_t stream) {
    const int*   bits = (const int*)d_in[0];
    const float* rrc  = (const float*)d_in[1];
    float*       out  = (float*)d_out;

    const int B = in_sizes[0] / NBITS;         // 256
    dim3 grid(B * (NS / QPB));                 // 8192 blocks
    qpsk_mod_kernel<<<grid, 256, 0, stream>>>(bits, rrc, out);
}